// Round 10
// baseline (283.600 us; speedup 1.0000x reference)
//
#include <hip/hip_runtime.h>
#include <hip/hip_bf16.h>
#include <cstdint>

// MultiHeadSelfAttention: B=4, N=2048, C=1024, H=16, D=64
// Ledger: R12 2ph=88.6; R13 8ph=87.5; R14 cohort=96.8; R15 direct-B=132.4;
//  R18 LDS-epi=90.5 (epilogue exonerated: WRITE_SIZE 48MB before AND after).
// R19: gemm_qkv + gemm_out K-loop sync only.
//  __syncthreads() drains vmcnt(0) EVERY K-step -> staging latency fully
//  serial (the m97 barrier-drain stall; fatal at K=1024's 16 steps/block).
//  Fix: LDS double-buffer (64KB), raw s_barrier pair + counted vmcnt(8) —
//  next tile's loads stay in flight across barriers, land under compute.
//  Epilogue = R12-exact scatter. attn/prep = R17-exact.
// R20: identical resubmit of R19 — round 9 was an infra failure (container
//  failed twice); R19 is still unbenched.

typedef __attribute__((ext_vector_type(8))) short short8;    // 8 bf16
typedef __attribute__((ext_vector_type(4))) float floatx4;

#if __has_builtin(__builtin_amdgcn_exp2f)
#define EXP2F(x) __builtin_amdgcn_exp2f(x)
#else
#define EXP2F(x) __expf((x) * 0.6931471805599453f)
#endif

__device__ __forceinline__ unsigned short f2bf(float f) {
  unsigned u = __float_as_uint(f);
  unsigned r = u + 0x7fffu + ((u >> 16) & 1u);   // RNE
  return (unsigned short)(r >> 16);
}

__device__ __forceinline__ void async16(const void* g, void* l) {
  __builtin_amdgcn_global_load_lds(
      (__attribute__((address_space(1))) void*)(void*)(uintptr_t)g,
      (__attribute__((address_space(3))) void*)l, 16, 0, 0);
}

// ------------------------------------------- prep: x cvt + 4x W^T (merged)
__global__ __launch_bounds__(256) void prep_kernel(
    const float* __restrict__ x, unsigned short* __restrict__ xb,
    const float* __restrict__ W0, const float* __restrict__ W1,
    const float* __restrict__ W2, const float* __restrict__ W3,
    unsigned short* __restrict__ T0, unsigned short* __restrict__ T1,
    unsigned short* __restrict__ T2, unsigned short* __restrict__ T3) {
  const int tid = threadIdx.x;
  int blk = blockIdx.x;
  if (blk < 8192) {               // ---- x f32 -> bf16
    int i = (blk * 256 + tid) * 4;
    float4 v = *(const float4*)(x + i);
    ushort4 o;
    o.x = f2bf(v.x); o.y = f2bf(v.y); o.z = f2bf(v.z); o.w = f2bf(v.w);
    *(ushort4*)(xb + i) = o;
  } else {                        // ---- W transpose+convert, 32x32 tiles
    int t = blk - 8192;
    int z = t >> 10, tile = t & 1023;
    const float* W = z == 0 ? W0 : z == 1 ? W1 : z == 2 ? W2 : W3;
    unsigned short* T = z == 0 ? T0 : z == 1 ? T1 : z == 2 ? T2 : T3;
    __shared__ float tb[32][33];
    int tx = tid & 31, ty = tid >> 5;            // 32 x 8
    int bx = (tile & 31) * 32, by = (tile >> 5) * 32;
#pragma unroll
    for (int i = 0; i < 4; ++i)
      tb[ty + i * 8][tx] = W[(size_t)(by + ty + i * 8) * 1024 + bx + tx];
    __syncthreads();
#pragma unroll
    for (int i = 0; i < 4; ++i)
      T[(size_t)(bx + ty + i * 8) * 1024 + by + tx] = f2bf(tb[tx][ty + i * 8]);
  }
}

// ------------------------------------------- fused QKV projection (M x 3072)
// 128x128 tile, BK=64, LDS DOUBLE-buffered (64KB): no vmcnt(0) drain in loop.
// Per K-step: barrier (compute t-1 done everywhere) -> stage t+1 into buf^1
// -> vmcnt(8) (own buf-t loads done) -> barrier (buf t staged everywhere)
// -> compute buf t. R12-exact frag layout + scatter epilogue.
__global__ __launch_bounds__(256) void gemm_qkv(
    const unsigned short* __restrict__ A, const unsigned short* __restrict__ BT,
    const float* __restrict__ bq, const float* __restrict__ bk,
    const float* __restrict__ bv,
    unsigned short* __restrict__ Qo, unsigned short* __restrict__ Ko,
    unsigned short* __restrict__ Vo) {
  constexpr int Kd = 1024;
  __shared__ unsigned short As[2][8192];   // 32 KB
  __shared__ unsigned short Bs[2][8192];   // 32 KB
  const int tid = threadIdx.x;
  const int wave = tid >> 6, lane = tid & 63;
  const int quad = lane >> 4, l16 = lane & 15;
  const int wm = (wave & 1) * 64, wn = (wave >> 1) * 64;
  const int m0 = blockIdx.x * 128, n0 = blockIdx.y * 128;
  const int mid = blockIdx.y >> 3;                 // 0=Q 1=K 2=V
  const float* bias = mid == 0 ? bq : mid == 1 ? bk : bv;
  const float scale = mid == 0 ? 0.180336880021082f : 1.0f;  // Q: 0.125*log2(e)

  floatx4 acc[4][4] = {};
  const unsigned short* Ag = A + (size_t)m0 * Kd;
  const unsigned short* Bg = BT + (size_t)n0 * Kd;

  // per-wave staging geometry (R12-identical): chunk p covers rows
  // (wave*4+p) quarter; c = chunk*64+lane -> row,(h,kp) within 64-k slab.
  const int c0 = wave * 4 * 64 + lane;

#define STAGE(S, k0)                                                          \
  { _Pragma("unroll") for (int p = 0; p < 4; ++p) {                           \
      int c = c0 + p * 64;                                                    \
      int h = c >> 9, row = (c >> 2) & 127, kp = c & 3;                       \
      async16(Ag + (size_t)row * Kd + (k0) + h * 32 + kp * 8,                 \
              (char*)As[S] + (size_t)(wave * 4 + p) * 1024);                  \
      async16(Bg + (size_t)row * Kd + (k0) + h * 32 + kp * 8,                 \
              (char*)Bs[S] + (size_t)(wave * 4 + p) * 1024); } }

  STAGE(0, 0);                                   // prologue: tile 0 -> buf0
#pragma unroll 1
  for (int t = 0; t < 16; ++t) {
    const int cur = t & 1;
    __builtin_amdgcn_s_barrier();                // all waves done compute(t-1)
    if (t < 15) {
      STAGE(cur ^ 1, (t + 1) * 64);              // prefetch t+1 (8 loads)
      asm volatile("s_waitcnt vmcnt(8)" ::: "memory");   // own buf-t loads done
    } else {
      asm volatile("s_waitcnt vmcnt(0)" ::: "memory");
    }
    __builtin_amdgcn_s_barrier();                // buf[cur] staged everywhere
    const unsigned short* Ac = As[cur];
    const unsigned short* Bc = Bs[cur];
#pragma unroll
    for (int ks = 0; ks < 2; ++ks) {
      short8 a[4], b[4];
#pragma unroll
      for (int i = 0; i < 4; ++i) {
        a[i] = *(const short8*)(Ac + ks * 4096 + (wm + i * 16 + l16) * 32 + quad * 8);
        b[i] = *(const short8*)(Bc + ks * 4096 + (wn + i * 16 + l16) * 32 + quad * 8);
      }
#pragma unroll
      for (int i = 0; i < 4; ++i)
#pragma unroll
        for (int j = 0; j < 4; ++j)
          acc[i][j] = __builtin_amdgcn_mfma_f32_16x16x32_bf16(a[i], b[j], acc[i][j], 0, 0, 0);
    }
  }
#undef STAGE

#pragma unroll
  for (int j = 0; j < 4; ++j) {
    int gcol = n0 + wn + j * 16 + l16;
    int cn = gcol & 1023;
    float bb = bias[cn];
    int h = cn >> 6, d = cn & 63;
#pragma unroll
    for (int i = 0; i < 4; ++i) {
      int rbase = m0 + wm + i * 16 + quad * 4;
#pragma unroll
      for (int r = 0; r < 4; ++r) {
        int row = rbase + r;
        unsigned short hv = f2bf((acc[i][j][r] + bb) * scale);
        int bi = row >> 11, ni = row & 2047;
        size_t bh = (size_t)bi * 16 + h;
        if (mid == 2) {   // V^T B-frag, key order interleaved: pos=(jk&15)*2|(jk>>4)
          int nt = d >> 4, vl = d & 15;
          int kq = ni >> 5, jk = ni & 31;
          int pos = ((jk & 15) << 1) | (jk >> 4);
          Vo[((bh * 64 + kq) * 4 + nt) * 512 + (pos >> 3) * 128 + vl * 8 + (pos & 7)] = hv;
        } else {          // Q/K frag: block (bh*128 + tok16)*2 + kk
          int kfg = ni >> 4, tl = ni & 15;
          int kk = d >> 5, dq = (d & 31) >> 3, dj = d & 7;
          unsigned short* outp = mid == 0 ? Qo : Ko;
          outp[((bh * 128 + kfg) * 2 + kk) * 512 + dq * 128 + tl * 8 + dj] = hv;
        }
      }
    }
  }
}

// --------------------------------------------------------------- attention
// R17-exact: 4 waves, no main-loop barriers, P parity dbuf + K-frag prefetch
// + setprio + V double-buffer.
__global__ __launch_bounds__(256, 3) void attn_kernel(
    const unsigned short* __restrict__ Qs, const unsigned short* __restrict__ Ksw,
    const unsigned short* __restrict__ Vsw, unsigned short* __restrict__ O) {
  __shared__ __align__(16) char smem[20480];

  const int tid = threadIdx.x, wave = tid >> 6, lane = tid & 63;
  const int quad = lane >> 4, l16 = lane & 15;
  const int wk = wave & 1, wqi = wave >> 1;
  int blk = blockIdx.x;
  int xcd = blk & 7, slot = blk >> 3;
  int bh = (slot & 7) * 8 + xcd, qb = slot >> 3;   // qb: 0..31 (64-row blocks)

  unsigned short* Pw0 = (unsigned short*)(smem + wave * 5120);
  unsigned short* Pw1 = (unsigned short*)(smem + wave * 5120 + 2560);

  // Q A-frags (2 row-tiles x 2 k-halves)
  short8 aq[2][2];
#pragma unroll
  for (int rt = 0; rt < 2; ++rt)
#pragma unroll
    for (int kk = 0; kk < 2; ++kk)
      aq[rt][kk] = *(const short8*)(Qs +
          (((size_t)bh * 128 + qb * 4 + wqi * 2 + rt) * 2 + kk) * 512 + lane * 8);

  short8 ones;
#pragma unroll
  for (int i = 0; i < 8; ++i) ones[i] = (short)0x3F80;   // bf16 1.0

  const float MSUB = 17.3123404906675611f;   // 12*log2(e); scores in log2 units
  floatx4 mneg;
#pragma unroll
  for (int i = 0; i < 4; ++i) mneg[i] = -MSUB;

  floatx4 acc_o[2][4] = {};
  floatx4 acc_l[2] = {};

  const unsigned short* kptr0 = Ksw + (size_t)bh * 128 * 2 * 512 + (size_t)wk * 32 * 2048;
  const unsigned short* vptr0 = Vsw + (size_t)bh * 64 * 4 * 512 + (size_t)wk * 32 * 2048;

  short8 kf0[2][2], kf1[2][2], vf0[4], vf1[4];
  floatx4 sacc[2][2];

#define LOAD_KF(dst, KT)                                                          \
  {                                                                               \
    _Pragma("unroll") for (int ct = 0; ct < 2; ++ct)                              \
        _Pragma("unroll") for (int kk = 0; kk < 2; ++kk)                          \
            dst[ct][kk] = *(const short8*)(kptr0 + (size_t)(KT)*2048 +            \
                                           (ct * 2 + kk) * 512 + lane * 8);       \
  }
#define LOAD_VF(dst, KT)                                                          \
  {                                                                               \
    _Pragma("unroll") for (int nt = 0; nt < 4; ++nt)                              \
        dst[nt] = *(const short8*)(vptr0 + (size_t)(KT)*2048 + nt * 512 + lane * 8); \
  }
#define QK_BLOCK(KF)                                                              \
  {                                                                               \
    __builtin_amdgcn_s_setprio(1);                                                \
    _Pragma("unroll") for (int rt = 0; rt < 2; ++rt)                              \
        _Pragma("unroll") for (int ct = 0; ct < 2; ++ct) {                        \
      sacc[rt][ct] = __builtin_amdgcn_mfma_f32_16x16x32_bf16(aq[rt][0], KF[ct][0], mneg, 0, 0, 0); \
      sacc[rt][ct] = __builtin_amdgcn_mfma_f32_16x16x32_bf16(aq[rt][1], KF[ct][1], sacc[rt][ct], 0, 0, 0); \
    }                                                                             \
    __builtin_amdgcn_s_setprio(0);                                                \
  }
#define EXP_WRITE(PBUF)                                                           \
  {                                                                               \
    _Pragma("unroll") for (int rt = 0; rt < 2; ++rt)                              \
        _Pragma("unroll") for (int r = 0; r < 4; ++r) {                           \
      float pe = EXP2F(sacc[rt][0][r]);                                           \
      float po = EXP2F(sacc[rt][1][r]);                                           \
      unsigned pk = __builtin_amdgcn_perm(__float_as_uint(po), __float_as_uint(pe), 0x07060302u); \
      ((unsigned*)((PBUF) + (rt * 16 + quad * 4 + r) * 40))[l16] = pk;            \
    }                                                                             \
  }
#define PV_BLOCK(PBUF, VF)                                                        \
  {                                                                               \
    __builtin_amdgcn_s_setprio(1);                                                \
    _Pragma("unroll") for (int rt = 0; rt < 2; ++rt) {                            \
      short8 ap = *(const short8*)((PBUF) + (rt * 16 + l16) * 40 + quad * 8);     \
      acc_l[rt] = __builtin_amdgcn_mfma_f32_16x16x32_bf16(ap, ones, acc_l[rt], 0, 0, 0); \
      _Pragma("unroll") for (int nt = 0; nt < 4; ++nt)                            \
          acc_o[rt][nt] = __builtin_amdgcn_mfma_f32_16x16x32_bf16(ap, VF[nt], acc_o[rt][nt], 0, 0, 0); \
    }                                                                             \
    __builtin_amdgcn_s_setprio(0);                                                \
  }

  // ---- prologue: K(0),K(1),V(0),V(1); QK(0); P(0)->Pw0
  LOAD_KF(kf0, 0);
  LOAD_KF(kf1, 1);
  LOAD_VF(vf0, 0);
  LOAD_VF(vf1, 1);
  QK_BLOCK(kf0);
  EXP_WRITE(Pw0);

  // ---- main: V(j) in vf[j&1]; P(j) in Pw[j&1]; K(j) in kf[j&1].
  for (int it = 0; it < 15; ++it) {
    const int i1 = 2 * it + 1, i2 = 2 * it + 2;
    // odd sub-iter (i1)
    LOAD_KF(kf0, i1 + 1);
    QK_BLOCK(kf1);
    PV_BLOCK(Pw0, vf0);       // PV(i1-1), V(i1-1) in vf0
    LOAD_VF(vf0, i1 + 1);     // V(i1+1) -> vf0
    EXP_WRITE(Pw1);
    // even sub-iter (i2)
    LOAD_KF(kf1, i2 + 1);
    QK_BLOCK(kf0);
    PV_BLOCK(Pw1, vf1);       // PV(i2-1), V(i2-1) in vf1
    LOAD_VF(vf1, i2 + 1);     // V(i2+1) -> vf1
    EXP_WRITE(Pw0);
  }
  // ---- tail: i = 31 (V(30) in vf0, V(31) in vf1 — already loaded)
  QK_BLOCK(kf1);
  PV_BLOCK(Pw0, vf0);         // PV(30)
  EXP_WRITE(Pw1);
  PV_BLOCK(Pw1, vf1);         // PV(31)

#undef LOAD_KF
#undef LOAD_VF
#undef QK_BLOCK
#undef EXP_WRITE
#undef PV_BLOCK

  // ---- combine key halves, normalize, store
  float* buf = (float*)smem + wqi * 2176;          // 32 x 68 f32
  float* lbuf = (float*)(smem + 17408);            // 64 f32
  __syncthreads();
  if (wk == 1) {
#pragma unroll
    for (int rt = 0; rt < 2; ++rt)
#pragma unroll
      for (int r = 0; r < 4; ++r) {
        int row = rt * 16 + quad * 4 + r;
#pragma unroll
        for (int nt = 0; nt < 4; ++nt)
          buf[row * 68 + nt * 16 + l16] = acc_o[rt][nt][r];
        if (l16 == 0) lbuf[wqi * 32 + row] = acc_l[rt][r];
      }
  }
  __syncthreads();
  if (wk == 0) {
    const int b = bh >> 4, h = bh & 15;
#pragma unroll
    for (int rt = 0; rt < 2; ++rt)
#pragma unroll
      for (int r = 0; r < 4; ++r) {
        int row = rt * 16 + quad * 4 + r;
        float linv = 1.0f / (acc_l[rt][r] + lbuf[wqi * 32 + row]);
        int grow = qb * 64 + wqi * 32 + row;
#pragma unroll
        for (int nt = 0; nt < 4; ++nt) {
          float v = (acc_o[rt][nt][r] + buf[row * 68 + nt * 16 + l16]) * linv;
          O[((size_t)b * 2048 + grow) * 1024 + h * 64 + nt * 16 + l16] = f2bf(v);
        }
      }
  }
}

// ------------------------------------------------------------- output GEMM
// Same R19 dbuf + counted-vmcnt transformation.
__global__ __launch_bounds__(256) void gemm_out(
    const unsigned short* __restrict__ A, const unsigned short* __restrict__ BT,
    const float* __restrict__ bias, float* __restrict__ of) {
  constexpr int Kd = 1024;
  __shared__ unsigned short As[2][8192];
  __shared__ unsigned short Bs[2][8192];
  const int tid = threadIdx.x;
  const int wave = tid >> 6, lane = tid & 63;
  const int quad = lane >> 4, l16 = lane & 15;
  const int wm = (wave & 1) * 64, wn = (wave >> 1) * 64;
  const int m0 = blockIdx.x * 128, n0 = blockIdx.y * 128;

  floatx4 acc[4][4] = {};
  const unsigned short* Ag = A + (size_t)m0 * Kd;
  const unsigned short* Bg = BT + (size_t)n0 * Kd;
  const int c0 = wave * 4 * 64 + lane;

#define STAGE(S, k0)                                                          \
  { _Pragma("unroll") for (int p = 0; p < 4; ++p) {                           \
      int c = c0 + p * 64;                                                    \
      int h = c >> 9, row = (c >> 2) & 127, kp = c & 3;                       \
      async16(Ag + (size_t)row * Kd + (k0) + h * 32 + kp * 8,                 \
              (char*)As[S] + (size_t)(wave * 4 + p) * 1024);                  \
      async16(Bg + (size_t)row * Kd + (k0) + h * 32 + kp * 8,                 \
              (char*)Bs[S] + (size_t)(wave * 4 + p) * 1024); } }

  STAGE(0, 0);
#pragma unroll 1
  for (int t = 0; t < 16; ++t) {
    const int cur = t & 1;
    __builtin_amdgcn_s_barrier();
    if (t < 15) {
      STAGE(cur ^ 1, (t + 1) * 64);
      asm volatile("s_waitcnt vmcnt(8)" ::: "memory");
    } else {
      asm volatile("s_waitcnt vmcnt(0)" ::: "memory");
    }
    __builtin_amdgcn_s_barrier();
    const unsigned short* Ac = As[cur];
    const unsigned short* Bc = Bs[cur];
#pragma unroll
    for (int ks = 0; ks < 2; ++ks) {
      short8 a[4], b[4];
#pragma unroll
      for (int i = 0; i < 4; ++i) {
        a[i] = *(const short8*)(Ac + ks * 4096 + (wm + i * 16 + l16) * 32 + quad * 8);
        b[i] = *(const short8*)(Bc + ks * 4096 + (wn + i * 16 + l16) * 32 + quad * 8);
      }
#pragma unroll
      for (int i = 0; i < 4; ++i)
#pragma unroll
        for (int j = 0; j < 4; ++j)
          acc[i][j] = __builtin_amdgcn_mfma_f32_16x16x32_bf16(a[i], b[j], acc[i][j], 0, 0, 0);
    }
  }
#undef STAGE

#pragma unroll
  for (int j = 0; j < 4; ++j) {
    int col = n0 + wn + j * 16 + l16;
    float bb = bias[col];
#pragma unroll
    for (int i = 0; i < 4; ++i) {
      int rbase = m0 + wm + i * 16 + quad * 4;
#pragma unroll
      for (int r = 0; r < 4; ++r)
        of[(size_t)(rbase + r) * 1024 + col] = acc[i][j][r] + bb;
    }
  }
}

// ---------------------------------------------------------------- launch
extern "C" void kernel_launch(void* const* d_in, const int* in_sizes, int n_in,
                              void* d_out, int out_size, void* d_ws, size_t ws_size,
                              hipStream_t stream) {
  const float* x  = (const float*)d_in[0];
  const float* Wq = (const float*)d_in[1];
  const float* bq = (const float*)d_in[2];
  const float* Wk = (const float*)d_in[3];
  const float* bk = (const float*)d_in[4];
  const float* Wv = (const float*)d_in[5];
  const float* bv = (const float*)d_in[6];
  const float* Wo = (const float*)d_in[7];
  const float* bo = (const float*)d_in[8];

  char* ws = (char*)d_ws;
  unsigned short* xb  = (unsigned short*)(ws);                 // 16 MiB
  unsigned short* wqt = (unsigned short*)(ws + (16u << 20));   // 2 MiB each, contiguous
  unsigned short* wkt = (unsigned short*)(ws + (18u << 20));
  unsigned short* wvt = (unsigned short*)(ws + (20u << 20));
  unsigned short* wot = (unsigned short*)(ws + (22u << 20));
  unsigned short* Qb  = (unsigned short*)(ws + (24u << 20));   // 16 MiB each
  unsigned short* Kb  = (unsigned short*)(ws + (40u << 20));
  unsigned short* Vtb = (unsigned short*)(ws + (56u << 20));
  unsigned short* Ob  = (unsigned short*)(ws + (72u << 20));   // total 88 MiB

  prep_kernel<<<dim3(12288), 256, 0, stream>>>(x, xb, Wq, Wk, Wv, Wo, wqt, wkt, wvt, wot);
  gemm_qkv<<<dim3(64, 24), 256, 0, stream>>>(xb, wqt, bq, bk, bv, Qb, Kb, Vtb);
  attn_kernel<<<dim3(2048), 256, 0, stream>>>(Qb, Kb, Vtb, Ob);
  gemm_out<<<dim3(64, 8), 256, 0, stream>>>(Ob, wot, bo, (float*)d_out);
}

// Round 11
// 280.331 us; speedup vs baseline: 1.0117x; 1.0117x over previous
//
#include <hip/hip_runtime.h>
#include <hip/hip_bf16.h>
#include <cstdint>

// MultiHeadSelfAttention: B=4, N=2048, C=1024, H=16, D=64
// Ledger: gemm_qkv R19 dbuf+vmcnt(8) < 87.5us (out of top-5; keep).
//  attn stuck 87.5-88 across all rounds -> now the critical kernel.
// R21 (delta from R20, attn only):
//  (a) P-buffer relayout [p=row&15][rt(80B)][176B stride] -> the two packed
//      P-words per (quad,r) are 20 dwords apart off one base: compiler DS
//      combiner emits ds_write2_b32 (8->4 write instrs/sub-iter; LDS pipe
//      is instr-overhead-bound). Writes 2-way banked, b128 reads 2-way,
//      16B aligned. smem 20480->22528 (Pw stride 5632/wave).
//  (b) bh-cohort remap: bh=(slot>>5)*8+xcd, qb=slot&31 -> 32 concurrent
//      blocks/XCD share ONE bh (K/V WS 512KB << 4MB L2; was 8 bh = 4MB).

typedef __attribute__((ext_vector_type(8))) short short8;    // 8 bf16
typedef __attribute__((ext_vector_type(4))) float floatx4;

#if __has_builtin(__builtin_amdgcn_exp2f)
#define EXP2F(x) __builtin_amdgcn_exp2f(x)
#else
#define EXP2F(x) __expf((x) * 0.6931471805599453f)
#endif

__device__ __forceinline__ unsigned short f2bf(float f) {
  unsigned u = __float_as_uint(f);
  unsigned r = u + 0x7fffu + ((u >> 16) & 1u);   // RNE
  return (unsigned short)(r >> 16);
}

__device__ __forceinline__ void async16(const void* g, void* l) {
  __builtin_amdgcn_global_load_lds(
      (__attribute__((address_space(1))) void*)(void*)(uintptr_t)g,
      (__attribute__((address_space(3))) void*)l, 16, 0, 0);
}

// ------------------------------------------- prep: x cvt + 4x W^T (merged)
__global__ __launch_bounds__(256) void prep_kernel(
    const float* __restrict__ x, unsigned short* __restrict__ xb,
    const float* __restrict__ W0, const float* __restrict__ W1,
    const float* __restrict__ W2, const float* __restrict__ W3,
    unsigned short* __restrict__ T0, unsigned short* __restrict__ T1,
    unsigned short* __restrict__ T2, unsigned short* __restrict__ T3) {
  const int tid = threadIdx.x;
  int blk = blockIdx.x;
  if (blk < 8192) {               // ---- x f32 -> bf16
    int i = (blk * 256 + tid) * 4;
    float4 v = *(const float4*)(x + i);
    ushort4 o;
    o.x = f2bf(v.x); o.y = f2bf(v.y); o.z = f2bf(v.z); o.w = f2bf(v.w);
    *(ushort4*)(xb + i) = o;
  } else {                        // ---- W transpose+convert, 32x32 tiles
    int t = blk - 8192;
    int z = t >> 10, tile = t & 1023;
    const float* W = z == 0 ? W0 : z == 1 ? W1 : z == 2 ? W2 : W3;
    unsigned short* T = z == 0 ? T0 : z == 1 ? T1 : z == 2 ? T2 : T3;
    __shared__ float tb[32][33];
    int tx = tid & 31, ty = tid >> 5;            // 32 x 8
    int bx = (tile & 31) * 32, by = (tile >> 5) * 32;
#pragma unroll
    for (int i = 0; i < 4; ++i)
      tb[ty + i * 8][tx] = W[(size_t)(by + ty + i * 8) * 1024 + bx + tx];
    __syncthreads();
#pragma unroll
    for (int i = 0; i < 4; ++i)
      T[(size_t)(bx + ty + i * 8) * 1024 + by + tx] = f2bf(tb[tx][ty + i * 8]);
  }
}

// ------------------------------------------- fused QKV projection (M x 3072)
// R19: 128x128 tile, BK=64, LDS dbuf (64KB), raw barriers + counted vmcnt(8).
__global__ __launch_bounds__(256) void gemm_qkv(
    const unsigned short* __restrict__ A, const unsigned short* __restrict__ BT,
    const float* __restrict__ bq, const float* __restrict__ bk,
    const float* __restrict__ bv,
    unsigned short* __restrict__ Qo, unsigned short* __restrict__ Ko,
    unsigned short* __restrict__ Vo) {
  constexpr int Kd = 1024;
  __shared__ unsigned short As[2][8192];   // 32 KB
  __shared__ unsigned short Bs[2][8192];   // 32 KB
  const int tid = threadIdx.x;
  const int wave = tid >> 6, lane = tid & 63;
  const int quad = lane >> 4, l16 = lane & 15;
  const int wm = (wave & 1) * 64, wn = (wave >> 1) * 64;
  const int m0 = blockIdx.x * 128, n0 = blockIdx.y * 128;
  const int mid = blockIdx.y >> 3;                 // 0=Q 1=K 2=V
  const float* bias = mid == 0 ? bq : mid == 1 ? bk : bv;
  const float scale = mid == 0 ? 0.180336880021082f : 1.0f;  // Q: 0.125*log2(e)

  floatx4 acc[4][4] = {};
  const unsigned short* Ag = A + (size_t)m0 * Kd;
  const unsigned short* Bg = BT + (size_t)n0 * Kd;
  const int c0 = wave * 4 * 64 + lane;

#define STAGE(S, k0)                                                          \
  { _Pragma("unroll") for (int p = 0; p < 4; ++p) {                           \
      int c = c0 + p * 64;                                                    \
      int h = c >> 9, row = (c >> 2) & 127, kp = c & 3;                       \
      async16(Ag + (size_t)row * Kd + (k0) + h * 32 + kp * 8,                 \
              (char*)As[S] + (size_t)(wave * 4 + p) * 1024);                  \
      async16(Bg + (size_t)row * Kd + (k0) + h * 32 + kp * 8,                 \
              (char*)Bs[S] + (size_t)(wave * 4 + p) * 1024); } }

  STAGE(0, 0);                                   // prologue: tile 0 -> buf0
#pragma unroll 1
  for (int t = 0; t < 16; ++t) {
    const int cur = t & 1;
    __builtin_amdgcn_s_barrier();                // all waves done compute(t-1)
    if (t < 15) {
      STAGE(cur ^ 1, (t + 1) * 64);              // prefetch t+1 (8 loads)
      asm volatile("s_waitcnt vmcnt(8)" ::: "memory");   // own buf-t loads done
    } else {
      asm volatile("s_waitcnt vmcnt(0)" ::: "memory");
    }
    __builtin_amdgcn_s_barrier();                // buf[cur] staged everywhere
    const unsigned short* Ac = As[cur];
    const unsigned short* Bc = Bs[cur];
#pragma unroll
    for (int ks = 0; ks < 2; ++ks) {
      short8 a[4], b[4];
#pragma unroll
      for (int i = 0; i < 4; ++i) {
        a[i] = *(const short8*)(Ac + ks * 4096 + (wm + i * 16 + l16) * 32 + quad * 8);
        b[i] = *(const short8*)(Bc + ks * 4096 + (wn + i * 16 + l16) * 32 + quad * 8);
      }
#pragma unroll
      for (int i = 0; i < 4; ++i)
#pragma unroll
        for (int j = 0; j < 4; ++j)
          acc[i][j] = __builtin_amdgcn_mfma_f32_16x16x32_bf16(a[i], b[j], acc[i][j], 0, 0, 0);
    }
  }
#undef STAGE

#pragma unroll
  for (int j = 0; j < 4; ++j) {
    int gcol = n0 + wn + j * 16 + l16;
    int cn = gcol & 1023;
    float bb = bias[cn];
    int h = cn >> 6, d = cn & 63;
#pragma unroll
    for (int i = 0; i < 4; ++i) {
      int rbase = m0 + wm + i * 16 + quad * 4;
#pragma unroll
      for (int r = 0; r < 4; ++r) {
        int row = rbase + r;
        unsigned short hv = f2bf((acc[i][j][r] + bb) * scale);
        int bi = row >> 11, ni = row & 2047;
        size_t bh = (size_t)bi * 16 + h;
        if (mid == 2) {   // V^T B-frag, key order interleaved: pos=(jk&15)*2|(jk>>4)
          int nt = d >> 4, vl = d & 15;
          int kq = ni >> 5, jk = ni & 31;
          int pos = ((jk & 15) << 1) | (jk >> 4);
          Vo[((bh * 64 + kq) * 4 + nt) * 512 + (pos >> 3) * 128 + vl * 8 + (pos & 7)] = hv;
        } else {          // Q/K frag: block (bh*128 + tok16)*2 + kk
          int kfg = ni >> 4, tl = ni & 15;
          int kk = d >> 5, dq = (d & 31) >> 3, dj = d & 7;
          unsigned short* outp = mid == 0 ? Qo : Ko;
          outp[((bh * 128 + kfg) * 2 + kk) * 512 + dq * 128 + tl * 8 + dj] = hv;
        }
      }
    }
  }
}

// --------------------------------------------------------------- attention
// 4 waves, no main-loop barriers, P parity dbuf + K-frag prefetch + setprio
// + V dbuf. R21: ds_write2-friendly P layout + bh-cohort block map.
__global__ __launch_bounds__(256, 3) void attn_kernel(
    const unsigned short* __restrict__ Qs, const unsigned short* __restrict__ Ksw,
    const unsigned short* __restrict__ Vsw, unsigned short* __restrict__ O) {
  __shared__ __align__(16) char smem[22528];

  const int tid = threadIdx.x, wave = tid >> 6, lane = tid & 63;
  const int quad = lane >> 4, l16 = lane & 15;
  const int wk = wave & 1, wqi = wave >> 1;
  int blk = blockIdx.x;
  int xcd = blk & 7, slot = blk >> 3;
  int qb = slot & 31;                      // R21: 32 qb of one bh contiguous
  int bh = (slot >> 5) * 8 + xcd;          // per-XCD cohort shares one bh

  // P buffers: [p=row&15 stride 176B][rt stride 80B][col dword l16*4B]
  unsigned short* Pw0 = (unsigned short*)(smem + wave * 5632);
  unsigned short* Pw1 = (unsigned short*)(smem + wave * 5632 + 2816);

  // Q A-frags (2 row-tiles x 2 k-halves)
  short8 aq[2][2];
#pragma unroll
  for (int rt = 0; rt < 2; ++rt)
#pragma unroll
    for (int kk = 0; kk < 2; ++kk)
      aq[rt][kk] = *(const short8*)(Qs +
          (((size_t)bh * 128 + qb * 4 + wqi * 2 + rt) * 2 + kk) * 512 + lane * 8);

  short8 ones;
#pragma unroll
  for (int i = 0; i < 8; ++i) ones[i] = (short)0x3F80;   // bf16 1.0

  const float MSUB = 17.3123404906675611f;   // 12*log2(e); scores in log2 units
  floatx4 mneg;
#pragma unroll
  for (int i = 0; i < 4; ++i) mneg[i] = -MSUB;

  floatx4 acc_o[2][4] = {};
  floatx4 acc_l[2] = {};

  const unsigned short* kptr0 = Ksw + (size_t)bh * 128 * 2 * 512 + (size_t)wk * 32 * 2048;
  const unsigned short* vptr0 = Vsw + (size_t)bh * 64 * 4 * 512 + (size_t)wk * 32 * 2048;

  short8 kf0[2][2], kf1[2][2], vf0[4], vf1[4];
  floatx4 sacc[2][2];

#define LOAD_KF(dst, KT)                                                          \
  {                                                                               \
    _Pragma("unroll") for (int ct = 0; ct < 2; ++ct)                              \
        _Pragma("unroll") for (int kk = 0; kk < 2; ++kk)                          \
            dst[ct][kk] = *(const short8*)(kptr0 + (size_t)(KT)*2048 +            \
                                           (ct * 2 + kk) * 512 + lane * 8);       \
  }
#define LOAD_VF(dst, KT)                                                          \
  {                                                                               \
    _Pragma("unroll") for (int nt = 0; nt < 4; ++nt)                              \
        dst[nt] = *(const short8*)(vptr0 + (size_t)(KT)*2048 + nt * 512 + lane * 8); \
  }
#define QK_BLOCK(KF)                                                              \
  {                                                                               \
    __builtin_amdgcn_s_setprio(1);                                                \
    _Pragma("unroll") for (int rt = 0; rt < 2; ++rt)                              \
        _Pragma("unroll") for (int ct = 0; ct < 2; ++ct) {                        \
      sacc[rt][ct] = __builtin_amdgcn_mfma_f32_16x16x32_bf16(aq[rt][0], KF[ct][0], mneg, 0, 0, 0); \
      sacc[rt][ct] = __builtin_amdgcn_mfma_f32_16x16x32_bf16(aq[rt][1], KF[ct][1], sacc[rt][ct], 0, 0, 0); \
    }                                                                             \
    __builtin_amdgcn_s_setprio(0);                                                \
  }
// write P row (rt*16 + quad*4 + r) -> p = quad*4+r (176B stride), sub = rt
// (80B). Base dword = quad*176 + l16; indices r*44 (+20 for rt=1): the pair
// is 20 dwords apart off one base -> DS combiner emits ds_write2_b32.
#define EXP_WRITE(PBUF)                                                           \
  {                                                                               \
    unsigned* wb = (unsigned*)((PBUF) + quad * 352 + l16 * 2);                    \
    _Pragma("unroll") for (int r = 0; r < 4; ++r) {                               \
      float pe0 = EXP2F(sacc[0][0][r]);                                           \
      float po0 = EXP2F(sacc[0][1][r]);                                           \
      float pe1 = EXP2F(sacc[1][0][r]);                                           \
      float po1 = EXP2F(sacc[1][1][r]);                                           \
      unsigned pk0 = __builtin_amdgcn_perm(__float_as_uint(po0), __float_as_uint(pe0), 0x07060302u); \
      unsigned pk1 = __builtin_amdgcn_perm(__float_as_uint(po1), __float_as_uint(pe1), 0x07060302u); \
      wb[r * 44] = pk0;                                                           \
      wb[r * 44 + 20] = pk1;                                                      \
    }                                                                             \
  }
// read P row (rt*16 + l16) -> p = l16 (176B), sub = rt (80B), quad*16B chunk
#define PV_BLOCK(PBUF, VF)                                                        \
  {                                                                               \
    __builtin_amdgcn_s_setprio(1);                                                \
    _Pragma("unroll") for (int rt = 0; rt < 2; ++rt) {                            \
      short8 ap = *(const short8*)((PBUF) + l16 * 88 + rt * 40 + quad * 8);       \
      acc_l[rt] = __builtin_amdgcn_mfma_f32_16x16x32_bf16(ap, ones, acc_l[rt], 0, 0, 0); \
      _Pragma("unroll") for (int nt = 0; nt < 4; ++nt)                            \
          acc_o[rt][nt] = __builtin_amdgcn_mfma_f32_16x16x32_bf16(ap, VF[nt], acc_o[rt][nt], 0, 0, 0); \
    }                                                                             \
    __builtin_amdgcn_s_setprio(0);                                                \
  }

  // ---- prologue: K(0),K(1),V(0),V(1); QK(0); P(0)->Pw0
  LOAD_KF(kf0, 0);
  LOAD_KF(kf1, 1);
  LOAD_VF(vf0, 0);
  LOAD_VF(vf1, 1);
  QK_BLOCK(kf0);
  EXP_WRITE(Pw0);

  // ---- main: V(j) in vf[j&1]; P(j) in Pw[j&1]; K(j) in kf[j&1].
  for (int it = 0; it < 15; ++it) {
    const int i1 = 2 * it + 1, i2 = 2 * it + 2;
    // odd sub-iter (i1)
    LOAD_KF(kf0, i1 + 1);
    QK_BLOCK(kf1);
    PV_BLOCK(Pw0, vf0);       // PV(i1-1), V(i1-1) in vf0
    LOAD_VF(vf0, i1 + 1);     // V(i1+1) -> vf0
    EXP_WRITE(Pw1);
    // even sub-iter (i2)
    LOAD_KF(kf1, i2 + 1);
    QK_BLOCK(kf0);
    PV_BLOCK(Pw1, vf1);       // PV(i2-1), V(i2-1) in vf1
    LOAD_VF(vf1, i2 + 1);     // V(i2+1) -> vf1
    EXP_WRITE(Pw0);
  }
  // ---- tail: i = 31 (V(30) in vf0, V(31) in vf1 — already loaded)
  QK_BLOCK(kf1);
  PV_BLOCK(Pw0, vf0);         // PV(30)
  EXP_WRITE(Pw1);
  PV_BLOCK(Pw1, vf1);         // PV(31)

#undef LOAD_KF
#undef LOAD_VF
#undef QK_BLOCK
#undef EXP_WRITE
#undef PV_BLOCK

  // ---- combine key halves, normalize, store
  float* buf = (float*)smem + wqi * 2176;          // 32 x 68 f32
  float* lbuf = (float*)(smem + 17408);            // 64 f32
  __syncthreads();
  if (wk == 1) {
#pragma unroll
    for (int rt = 0; rt < 2; ++rt)
#pragma unroll
      for (int r = 0; r < 4; ++r) {
        int row = rt * 16 + quad * 4 + r;
#pragma unroll
        for (int nt = 0; nt < 4; ++nt)
          buf[row * 68 + nt * 16 + l16] = acc_o[rt][nt][r];
        if (l16 == 0) lbuf[wqi * 32 + row] = acc_l[rt][r];
      }
  }
  __syncthreads();
  if (wk == 0) {
    const int b = bh >> 4, h = bh & 15;
#pragma unroll
    for (int rt = 0; rt < 2; ++rt)
#pragma unroll
      for (int r = 0; r < 4; ++r) {
        int row = rt * 16 + quad * 4 + r;
        float linv = 1.0f / (acc_l[rt][r] + lbuf[wqi * 32 + row]);
        int grow = qb * 64 + wqi * 32 + row;
#pragma unroll
        for (int nt = 0; nt < 4; ++nt) {
          float v = (acc_o[rt][nt][r] + buf[row * 68 + nt * 16 + l16]) * linv;
          O[((size_t)b * 2048 + grow) * 1024 + h * 64 + nt * 16 + l16] = f2bf(v);
        }
      }
  }
}

// ------------------------------------------------------------- output GEMM
// R19 dbuf + counted-vmcnt.
__global__ __launch_bounds__(256) void gemm_out(
    const unsigned short* __restrict__ A, const unsigned short* __restrict__ BT,
    const float* __restrict__ bias, float* __restrict__ of) {
  constexpr int Kd = 1024;
  __shared__ unsigned short As[2][8192];
  __shared__ unsigned short Bs[2][8192];
  const int tid = threadIdx.x;
  const int wave = tid >> 6, lane = tid & 63;
  const int quad = lane >> 4, l16 = lane & 15;
  const int wm = (wave & 1) * 64, wn = (wave >> 1) * 64;
  const int m0 = blockIdx.x * 128, n0 = blockIdx.y * 128;

  floatx4 acc[4][4] = {};
  const unsigned short* Ag = A + (size_t)m0 * Kd;
  const unsigned short* Bg = BT + (size_t)n0 * Kd;
  const int c0 = wave * 4 * 64 + lane;

#define STAGE(S, k0)                                                          \
  { _Pragma("unroll") for (int p = 0; p < 4; ++p) {                           \
      int c = c0 + p * 64;                                                    \
      int h = c >> 9, row = (c >> 2) & 127, kp = c & 3;                       \
      async16(Ag + (size_t)row * Kd + (k0) + h * 32 + kp * 8,                 \
              (char*)As[S] + (size_t)(wave * 4 + p) * 1024);                  \
      async16(Bg + (size_t)row * Kd + (k0) + h * 32 + kp * 8,                 \
              (char*)Bs[S] + (size_t)(wave * 4 + p) * 1024); } }

  STAGE(0, 0);
#pragma unroll 1
  for (int t = 0; t < 16; ++t) {
    const int cur = t & 1;
    __builtin_amdgcn_s_barrier();
    if (t < 15) {
      STAGE(cur ^ 1, (t + 1) * 64);
      asm volatile("s_waitcnt vmcnt(8)" ::: "memory");
    } else {
      asm volatile("s_waitcnt vmcnt(0)" ::: "memory");
    }
    __builtin_amdgcn_s_barrier();
    const unsigned short* Ac = As[cur];
    const unsigned short* Bc = Bs[cur];
#pragma unroll
    for (int ks = 0; ks < 2; ++ks) {
      short8 a[4], b[4];
#pragma unroll
      for (int i = 0; i < 4; ++i) {
        a[i] = *(const short8*)(Ac + ks * 4096 + (wm + i * 16 + l16) * 32 + quad * 8);
        b[i] = *(const short8*)(Bc + ks * 4096 + (wn + i * 16 + l16) * 32 + quad * 8);
      }
#pragma unroll
      for (int i = 0; i < 4; ++i)
#pragma unroll
        for (int j = 0; j < 4; ++j)
          acc[i][j] = __builtin_amdgcn_mfma_f32_16x16x32_bf16(a[i], b[j], acc[i][j], 0, 0, 0);
    }
  }
#undef STAGE

#pragma unroll
  for (int j = 0; j < 4; ++j) {
    int col = n0 + wn + j * 16 + l16;
    float bb = bias[col];
#pragma unroll
    for (int i = 0; i < 4; ++i) {
      int rbase = m0 + wm + i * 16 + quad * 4;
#pragma unroll
      for (int r = 0; r < 4; ++r)
        of[(size_t)(rbase + r) * 1024 + col] = acc[i][j][r] + bb;
    }
  }
}

// ---------------------------------------------------------------- launch
extern "C" void kernel_launch(void* const* d_in, const int* in_sizes, int n_in,
                              void* d_out, int out_size, void* d_ws, size_t ws_size,
                              hipStream_t stream) {
  const float* x  = (const float*)d_in[0];
  const float* Wq = (const float*)d_in[1];
  const float* bq = (const float*)d_in[2];
  const float* Wk = (const float*)d_in[3];
  const float* bk = (const float*)d_in[4];
  const float* Wv = (const float*)d_in[5];
  const float* bv = (const float*)d_in[6];
  const float* Wo = (const float*)d_in[7];
  const float* bo = (const float*)d_in[8];

  char* ws = (char*)d_ws;
  unsigned short* xb  = (unsigned short*)(ws);                 // 16 MiB
  unsigned short* wqt = (unsigned short*)(ws + (16u << 20));   // 2 MiB each, contiguous
  unsigned short* wkt = (unsigned short*)(ws + (18u << 20));
  unsigned short* wvt = (unsigned short*)(ws + (20u << 20));
  unsigned short* wot = (unsigned short*)(ws + (22u << 20));
  unsigned short* Qb  = (unsigned short*)(ws + (24u << 20));   // 16 MiB each
  unsigned short* Kb  = (unsigned short*)(ws + (40u << 20));
  unsigned short* Vtb = (unsigned short*)(ws + (56u << 20));
  unsigned short* Ob  = (unsigned short*)(ws + (72u << 20));   // total 88 MiB

  prep_kernel<<<dim3(12288), 256, 0, stream>>>(x, xb, Wq, Wk, Wv, Wo, wqt, wkt, wvt, wot);
  gemm_qkv<<<dim3(64, 24), 256, 0, stream>>>(xb, wqt, bq, bk, bv, Qb, Kb, Vtb);
  attn_kernel<<<dim3(2048), 256, 0, stream>>>(Qb, Kb, Vtb, Ob);
  gemm_out<<<dim3(64, 8), 256, 0, stream>>>(Ob, wot, bo, (float*)d_out);
}